// Round 9
// baseline (2579.086 us; speedup 1.0000x reference)
//
#include <hip/hip_runtime.h>
#include <hip/hip_cooperative_groups.h>

namespace cg = cooperative_groups;

#define IDX_BITS 20
#define IDX_MASK ((1u << IDX_BITS) - 1)
#define NTHREADS 1024
#define MAX_GRID 512
#define T1 49152          // grid-sync tier while alive > T1
#define TB2 64            // tier-2 block count (spin barrier)
#define T2 2048           // tier-2 while alive > T2; below: LDS tier-3
#define GRID_ROUND_CAP 16
#define MAX_ROUNDS 8000
#define SC_CAP 1024
#define SV_CAP 4096
#define TN 2048           // tier-3 LDS capacity (dense vertices)
#define TD 8              // fixed adjacency slots per dense vertex
#define OVCAP 1024        // overflow edge pairs

typedef unsigned long long u64;

// All edges are intra-segment, so the per-edge comparison key drops seg:
// key = (~float_bits(hier) << 20) | v ; smaller = earlier in processing order.
__device__ __forceinline__ u64 pack_key(float h, int v) {
  return ((u64)(~__float_as_uint(h)) << IDX_BITS) | (unsigned)v;
}

struct Ctx {
  const int* __restrict__ neighs;
  const float* __restrict__ hier;
  const int* __restrict__ row_splits;
  int V, K, nseg;
  u64* assign;       // [V] min grabber key; ~0 = alive; == own key -> decided centre
  int* tag;          // [V] "blocked at round r" tags (global tiers)
  int* dense_map;    // [V] global id -> tier-3 dense id (init -1)
  int* listA;        // [V] frontier ping
  int* listB;        // [V] frontier pong
  u64* centre_key;   // [V] full key incl. seg (for global ranking)
  int* centre_v;     // [V]
  int* rank_of;      // [V]
  int* cnt;          // [0,1] survivor ctrs (parity), [2] nC, [3] xbar, [4] claim, [8+s] seg
  int* out_sel;
  int* out_rs;
  int* out_gg;
};

// Monotonic arrive-counter barrier for the TB2 group. threadfence on both
// sides (L1 invalidate) preserves the cross-round freshness argument.
__device__ __forceinline__ void xbar(int* bar, int target) {
  __syncthreads();
  __threadfence();
  if (threadIdx.x == 0) {
    __hip_atomic_fetch_add(bar, 1, __ATOMIC_RELEASE, __HIP_MEMORY_SCOPE_AGENT);
    while (__hip_atomic_load(bar, __ATOMIC_ACQUIRE, __HIP_MEMORY_SCOPE_AGENT) < target)
      __builtin_amdgcn_s_sleep(2);
  }
  __syncthreads();
  __threadfence();
}

union SMem {
  struct { int sc_list[SC_CAP]; int sv_list[SV_CAP]; } l;  // tier-1/2 flush staging
  u64 shp[NTHREADS];                                       // rank phase
  struct {                                                 // tier-3 LDS subgraph
    u64 key[TN];                  // 16 KB
    int u_arr[TN];                //  8 KB
    int deg[TN];                  //  8 KB
    unsigned short adj[TN * TD];  // 32 KB
    int ov[OVCAP];                //  4 KB  (du<<16)|dw
    unsigned short tagl[TN];      //  4 KB
    unsigned int bits[TN / 32];   // 256 B  alive bitmask
    unsigned char isc[TN];        //  2 KB  is-centre (for ov kills)
  } t;                            // ~74 KB -> 2 blocks/CU
};

__global__ void __launch_bounds__(NTHREADS, 8) cluster_kernel(Ctx c) {
  cg::grid_group grid = cg::this_grid();
  const int tid = blockIdx.x * blockDim.x + threadIdx.x;
  const int nthr = gridDim.x * blockDim.x;
  const int V = c.V, K = c.K;
  const int ql = threadIdx.x & 15;          // lane within quarter-wave
  const int bq = threadIdx.x >> 4;          // quarter id within block (64)
  const int NBQ = NTHREADS >> 4;

  __shared__ SMem sm;
  __shared__ int sc_cnt, sv_cnt, sc_base, sv_base, claim_sh;
  __shared__ int t_n, t_alive, t_fail, ov_cnt2;
  __shared__ int seg_hist[8];

  auto record_direct = [&](int v, u64 pv) {
    int slot = atomicAdd(&c.cnt[2], 1);
    int seg = 0;
    for (int t = 1; t < c.nseg; ++t) seg += (v >= c.row_splits[t]);
    c.centre_v[slot] = v;
    c.centre_key[slot] = ((u64)seg << 52) | pv;
    atomicAdd(&c.cnt[8 + seg], 1);
  };

  // Quarter-wave (16 lanes) per vertex: coalesced 64B row reads + 4 vertices
  // in flight per wave (r7 lesson: thread-per-vertex loses coalescing).
  auto phaseB = [&](const int* rl, int an, int r, int qstart, int qstride) {
    if (K == 96) {
      for (int i = qstart; i < an; i += qstride) {
        int u = rl ? rl[i] : i;
        u64 pu = pack_key(c.hier[u], u);
        if (c.assign[u] <= pu) continue;
        const int* row = c.neighs + (size_t)u * 96;
        int w[6];
#pragma unroll
        for (int t = 0; t < 6; ++t) w[t] = row[ql + 16 * t];
#pragma unroll
        for (int t = 0; t < 6; ++t)
          if (pack_key(c.hier[w[t]], w[t]) > pu) c.tag[w[t]] = r;
      }
    } else {
      for (int i = qstart; i < an; i += qstride) {
        int u = rl ? rl[i] : i;
        u64 pu = pack_key(c.hier[u], u);
        if (c.assign[u] <= pu) continue;
        const int* row = c.neighs + (size_t)u * K;
        for (int j = ql; j < K; j += 16) {
          int w = row[j];
          if (pack_key(c.hier[w], w) > pu) c.tag[w] = r;
        }
      }
    }
  };
  // Unguarded atomicMin grabs: junk values > target's own key are inert.
  auto phaseC = [&](const int* rl, int* wl, int* survc, int an, int r,
                    int qstart, int qstride) {
    for (int i = qstart; i < an; i += qstride) {
      int u = rl ? rl[i] : i;
      u64 pu = pack_key(c.hier[u], u);
      if (c.assign[u] <= pu) continue;
      if (c.tag[u] != r) {
        const int* row = c.neighs + (size_t)u * K;
        for (int j = ql; j < K; j += 16) atomicMin(&c.assign[row[j]], pu);
        if (ql == 0) {
          int s = atomicAdd(&sc_cnt, 1);
          if (s < SC_CAP) sm.l.sc_list[s] = u; else record_direct(u, pu);
        }
      } else if (ql == 0) {
        u64 y = __hip_atomic_load(&c.assign[u], __ATOMIC_RELAXED, __HIP_MEMORY_SCOPE_AGENT);
        if (y > pu) {
          int s = atomicAdd(&sv_cnt, 1);
          if (s < SV_CAP) sm.l.sv_list[s] = u;
          else { int g = atomicAdd(survc, 1); wl[g] = u; }
        }
      }
    }
  };
  auto flush_block = [&](int* wl, int* survc) {
    __syncthreads();
    int nsc = min(sc_cnt, SC_CAP), nsv = min(sv_cnt, SV_CAP);
    if (threadIdx.x == 0 && nsc) sc_base = atomicAdd(&c.cnt[2], nsc);
    if (threadIdx.x == 0 && nsv) sv_base = atomicAdd(survc, nsv);
    if (threadIdx.x < 8) seg_hist[threadIdx.x] = 0;
    __syncthreads();
    for (int i = threadIdx.x; i < nsv; i += blockDim.x) wl[sv_base + i] = sm.l.sv_list[i];
    for (int i = threadIdx.x; i < nsc; i += blockDim.x) {
      int v = sm.l.sc_list[i];
      int seg = 0;
      for (int t = 1; t < c.nseg; ++t) seg += (v >= c.row_splits[t]);
      c.centre_v[sc_base + i] = v;
      c.centre_key[sc_base + i] = ((u64)seg << 52) | pack_key(c.hier[v], v);
      atomicAdd(&seg_hist[seg], 1);
    }
    __syncthreads();
    if (threadIdx.x < c.nseg) {
      int h = seg_hist[threadIdx.x];
      if (h) atomicAdd(&c.cnt[8 + threadIdx.x], h);
    }
    __syncthreads();
    if (threadIdx.x == 0) { sc_cnt = 0; sv_cnt = 0; }
  };

  if (threadIdx.x == 0) { sc_cnt = 0; sv_cnt = 0; }

  // ================= tier 1: grid-sync rounds (huge frontiers) =================
  int aliveN = V, r = 0;
  {
    const int qg = tid >> 4, nq = nthr >> 4;
    while (true) {
      const int* rl = (r & 1) ? c.listA : c.listB;
      int* wl = (r & 1) ? c.listB : c.listA;
      if (tid == 0) c.cnt[(r + 1) & 1] = 0;
      phaseB(r ? rl : nullptr, aliveN, r, qg, nq);
      __threadfence();
      grid.sync();
      phaseC(r ? rl : nullptr, wl, &c.cnt[(r + 1) & 1], aliveN, r, qg, nq);
      flush_block(wl, &c.cnt[(r + 1) & 1]);
      __threadfence();
      grid.sync();
      aliveN = c.cnt[(r + 1) & 1];
      ++r;
      if (aliveN == 0 || aliveN <= T1 || r >= GRID_ROUND_CAP) break;
    }
  }

  // ================= tiers 2+3 =================
  if (aliveN > 0) {
    if (threadIdx.x == 0) claim_sh = atomicAdd(&c.cnt[4], 1);
    __syncthreads();
    const int trank = claim_sh;
    int an = aliveN, tr = r;

    // tier 2: TB2 blocks, spin barrier, mid frontiers
    if (trank < TB2 && an > T2) {
      const int qstart = trank * NBQ + bq;
      const int qstride = TB2 * NBQ;
      int ep = 0;
      while (true) {
        const int* rl = (tr & 1) ? c.listA : c.listB;
        int* wl = (tr & 1) ? c.listB : c.listA;
        if (trank == 0 && threadIdx.x == 0) c.cnt[(tr + 1) & 1] = 0;
        phaseB(rl, an, tr, qstart, qstride);
        xbar(&c.cnt[3], TB2 * (++ep));
        phaseC(rl, wl, &c.cnt[(tr + 1) & 1], an, tr, qstart, qstride);
        flush_block(wl, &c.cnt[(tr + 1) & 1]);
        xbar(&c.cnt[3], TB2 * (++ep));
        an = c.cnt[(tr + 1) & 1];
        ++tr;
        if (an == 0 || an <= T2 || tr >= MAX_ROUNDS) break;
      }
    }

    // tier 3: block 0, LDS-resident subgraph (zero global traffic per level
    // except one-shot centre grabs). Fallback to global rounds on overflow.
    if (trank == 0 && an > 0) {
      const int* rl = (tr & 1) ? c.listA : c.listB;
      bool use_lds = (an <= TN);
      int n = 0;
      if (use_lds) {
        if (threadIdx.x == 0) { t_n = 0; t_fail = 0; ov_cnt2 = 0; }
        __syncthreads();
        // entry: compact alive (fresh re-check) into dense LDS set
        for (int i = threadIdx.x; i < an; i += NTHREADS) {
          int u = rl[i];
          u64 pu = pack_key(c.hier[u], u);
          u64 y = __hip_atomic_load(&c.assign[u], __ATOMIC_RELAXED, __HIP_MEMORY_SCOPE_AGENT);
          if (y > pu) {
            int d = atomicAdd(&t_n, 1);
            sm.t.u_arr[d] = u;
            sm.t.key[d] = pu;
          }
        }
        __syncthreads();
        n = t_n;
        for (int i = threadIdx.x; i < TN / 32; i += NTHREADS) sm.t.bits[i] = 0;
        for (int d = threadIdx.x; d < n; d += NTHREADS) {
          c.dense_map[sm.t.u_arr[d]] = d;
          sm.t.deg[d] = 0;
          sm.t.tagl[d] = 0xFFFFu;
          sm.t.isc[d] = 0;
        }
        if (threadIdx.x == 0) t_alive = n;
        __syncthreads();
        for (int d = threadIdx.x; d < n; d += NTHREADS)
          atomicOr(&sm.t.bits[d >> 5], 1u << (d & 31));
        __syncthreads();
        // filtered adjacency: only later+alive-at-entry neighbours matter for
        // blocking; quarter-wave per dense vertex, 1 dense_map gather per edge.
        for (int d = bq; d < n; d += NBQ) {
          int u = sm.t.u_arr[d];
          u64 pu = sm.t.key[d];
          const int* row = c.neighs + (size_t)u * K;
          for (int j = ql; j < K; j += 16) {
            int w = row[j];
            int dw = c.dense_map[w];
            if (dw >= 0 && sm.t.key[dw] > pu) {
              int s = atomicAdd(&sm.t.deg[d], 1);
              if (s < TD) sm.t.adj[d * TD + s] = (unsigned short)dw;
              else {
                int o = atomicAdd(&ov_cnt2, 1);
                if (o < OVCAP) sm.t.ov[o] = (d << 16) | dw;
                else t_fail = 1;
              }
            }
          }
        }
        __syncthreads();
        if (t_fail) use_lds = false;
      }

      if (use_lds) {
        const int nov = min(ov_cnt2, OVCAP);
        int rounds = 0;
        while (t_alive > 0 && rounds < 4096) {
          const unsigned short tg = (unsigned short)(tr & 0xffff);
          // B: alive vertices tag their filtered (later+alive-at-entry) adj
          for (int d = threadIdx.x; d < n; d += NTHREADS) {
            if (sm.t.bits[d >> 5] & (1u << (d & 31))) {
              int dg = min(sm.t.deg[d], TD);
              for (int s = 0; s < dg; ++s) sm.t.tagl[sm.t.adj[d * TD + s]] = tg;
            }
          }
          for (int o = threadIdx.x; o < nov; o += NTHREADS) {
            int pr = sm.t.ov[o], df = pr >> 16;
            if (sm.t.bits[df >> 5] & (1u << (df & 31))) sm.t.tagl[pr & 0xffff] = tg;
          }
          __syncthreads();
          // C: untagged+alive -> centre. Kills are safe mid-phase: every kill
          // target was tagged this round (the centre was alive in B), so no
          // kill can change a decision.
          for (int d = threadIdx.x; d < n; d += NTHREADS) {
            if ((sm.t.bits[d >> 5] & (1u << (d & 31))) && sm.t.tagl[d] != tg) {
              sm.t.isc[d] = 1;
              unsigned int m = 1u << (d & 31);
              unsigned int old = atomicAnd(&sm.t.bits[d >> 5], ~m);
              if (old & m) atomicSub(&t_alive, 1);
              int u = sm.t.u_arr[d];
              u64 pu = sm.t.key[d];
              const int* row = c.neighs + (size_t)u * K;   // L2-hot
              for (int j = 0; j < K; ++j) atomicMin(&c.assign[row[j]], pu);
              record_direct(u, pu);
              int dg = min(sm.t.deg[d], TD);
              for (int s = 0; s < dg; ++s) {
                int dw = sm.t.adj[d * TD + s];
                unsigned int mw = 1u << (dw & 31);
                unsigned int ow = atomicAnd(&sm.t.bits[dw >> 5], ~mw);
                if (ow & mw) atomicSub(&t_alive, 1);
              }
            }
          }
          __syncthreads();
          // K: overflow-edge kills by centres (historical re-kills harmless)
          for (int o = threadIdx.x; o < nov; o += NTHREADS) {
            int pr = sm.t.ov[o];
            if (sm.t.isc[pr >> 16]) {
              int dw = pr & 0xffff;
              unsigned int mw = 1u << (dw & 31);
              unsigned int ow = atomicAnd(&sm.t.bits[dw >> 5], ~mw);
              if (ow & mw) atomicSub(&t_alive, 1);
            }
          }
          __syncthreads();
          ++tr; ++rounds;
        }
      } else {
        // global fallback (r8 tier-3): single block, global tag/list rounds
        while (an > 0 && tr < MAX_ROUNDS) {
          const int* frl = (tr & 1) ? c.listA : c.listB;
          int* fwl = (tr & 1) ? c.listB : c.listA;
          if (threadIdx.x == 0) c.cnt[(tr + 1) & 1] = 0;
          phaseB(frl, an, tr, bq, NBQ);
          __threadfence(); __syncthreads();
          phaseC(frl, fwl, &c.cnt[(tr + 1) & 1], an, tr, bq, NBQ);
          flush_block(fwl, &c.cnt[(tr + 1) & 1]);
          __threadfence(); __syncthreads();
          an = c.cnt[(tr + 1) & 1];
          ++tr;
        }
      }
    }
  }
  __threadfence();
  grid.sync();

  // ================= centre ranks: O(nC^2) LDS-tiled counting =================
  int nC = c.cnt[2];
  if ((long long)blockIdx.x * blockDim.x < (long long)nC) {
    bool have = tid < nC;
    u64 mykey = have ? c.centre_key[tid] : 0;
    int myv = have ? c.centre_v[tid] : 0;
    int myrank = 0;
    for (int cs = 0; cs < nC; cs += NTHREADS) {
      int j = cs + threadIdx.x;
      sm.shp[threadIdx.x] = (j < nC) ? c.centre_key[j] : ~0ull;
      __syncthreads();
      int lim = min(NTHREADS, nC - cs);
      for (int t = 0; t < lim; ++t) myrank += (sm.shp[t] < mykey) ? 1 : 0;
      __syncthreads();
    }
    if (have) {
      c.out_sel[myrank] = myv;     // rank among centre keys == cumsum position
      c.rank_of[myv] = myrank;
    }
  }
  if (tid == 0) {
    int run = 0;
    c.out_rs[0] = 0;
    for (int s = 0; s < c.nseg; ++s) { run += c.cnt[8 + s]; c.out_rs[s + 1] = run; }
  }
  __threadfence();
  grid.sync();

  // ================= ggather =================
  for (int v = tid; v < V; v += nthr) {
    u64 y = c.assign[v];
    u64 pv = pack_key(c.hier[v], v);
    int ctr = (y < pv) ? (int)(y & IDX_MASK) : v;   // y==pv -> centre -> self
    c.out_gg[v] = c.rank_of[ctr];
  }
}

extern "C" void kernel_launch(void* const* d_in, const int* in_sizes, int n_in,
                              void* d_out, int out_size, void* d_ws, size_t ws_size,
                              hipStream_t stream) {
  Ctx c;
  c.neighs = (const int*)d_in[0];
  c.hier = (const float*)d_in[1];
  c.row_splits = (const int*)d_in[2];
  c.V = in_sizes[1];
  c.K = in_sizes[0] / c.V;
  c.nseg = in_sizes[2] - 1;

  char* pm = (char*)d_ws;
  const size_t V = (size_t)c.V;
  c.assign = (u64*)pm;        pm += V * 8;
  c.tag = (int*)pm;           pm += V * 4;
  c.dense_map = (int*)pm;     pm += V * 4;
  size_t ff_bytes = V * 16;   // assign -> ~0 (alive), tag -> -1, dense_map -> -1
  c.listA = (int*)pm;         pm += V * 4;
  c.listB = (int*)pm;         pm += V * 4;
  c.centre_key = (u64*)pm;    pm += V * 8;
  c.centre_v = (int*)pm;      pm += V * 4;
  c.rank_of = (int*)pm;       pm += V * 4;
  c.cnt = (int*)pm;           pm += 64 * 4;

  int* out = (int*)d_out;
  c.out_sel = out;
  c.out_rs = out + c.V;
  c.out_gg = out + c.V + c.nseg + 1;

  hipMemsetAsync(d_ws, 0xFF, ff_bytes, stream);
  hipMemsetAsync((void*)c.cnt, 0, 64 * 4, stream);
  hipMemsetAsync((void*)c.out_sel, 0xFF, V * 4, stream);

  int dev = 0, nCU = 0, maxB = 0;
  hipGetDevice(&dev);
  hipDeviceGetAttribute(&nCU, hipDeviceAttributeMultiprocessorCount, dev);
  hipOccupancyMaxActiveBlocksPerMultiprocessor(&maxB, cluster_kernel, NTHREADS, 0);
  if (nCU <= 0) nCU = 256;
  if (maxB <= 0) maxB = 1;
  int grid = nCU * maxB;
  if (grid > MAX_GRID) grid = MAX_GRID;

  void* args[] = { &c };
  hipLaunchCooperativeKernel((void*)cluster_kernel, dim3(grid), dim3(NTHREADS),
                             args, 0, stream);
}

// Round 10
// 2350.428 us; speedup vs baseline: 1.0973x; 1.0973x over previous
//
#include <hip/hip_runtime.h>
#include <hip/hip_cooperative_groups.h>

namespace cg = cooperative_groups;

#define IDX_BITS 20
#define IDX_MASK ((1u << IDX_BITS) - 1)
#define NTHREADS 1024
#define MAX_GRID 512
#define T1 49152          // grid-sync tier while alive > T1
#define TB2 16            // tier-2 block count (r9 lesson: 64-block spin barrier regresses)
#define T2 2048           // tier-2 while alive > T2; below: LDS tier-3
#define GRID_ROUND_CAP 16
#define MAX_ROUNDS 8000
#define SC_CAP 1024
#define SV_CAP 4096
#define TN 2048           // tier-3 LDS capacity (dense vertices)
#define TD 8              // fixed adjacency slots per dense vertex
#define OVCAP 1024        // overflow edge pairs

typedef unsigned long long u64;

// All edges are intra-segment, so the per-edge comparison key drops seg:
// key = (~float_bits(hier) << 20) | v ; smaller = earlier in processing order.
__device__ __forceinline__ u64 pack_key(float h, int v) {
  return ((u64)(~__float_as_uint(h)) << IDX_BITS) | (unsigned)v;
}

struct Ctx {
  const int* __restrict__ neighs;
  const float* __restrict__ hier;
  const int* __restrict__ row_splits;
  int V, K, nseg;
  u64* assign;       // [V] min grabber key; ~0 = alive; == own key -> decided centre
  int* tag;          // [V] "blocked at round r" tags (global tiers)
  int* dense_map;    // [V] global id -> tier-3 dense id (init -1)
  int* listA;        // [V] frontier ping
  int* listB;        // [V] frontier pong
  u64* centre_key;   // [V] full key incl. seg (for global ranking)
  int* centre_v;     // [V]
  int* rank_of;      // [V]
  int* cnt;          // [0,1] survivor ctrs (parity), [2] nC, [3] xbar, [4] claim, [8+s] seg
  int* out_sel;
  int* out_rs;
  int* out_gg;
};

// Monotonic arrive-counter barrier for the TB2 group. threadfence on both
// sides (L1 invalidate) preserves the cross-round freshness argument.
__device__ __forceinline__ void xbar(int* bar, int target) {
  __syncthreads();
  __threadfence();
  if (threadIdx.x == 0) {
    __hip_atomic_fetch_add(bar, 1, __ATOMIC_RELEASE, __HIP_MEMORY_SCOPE_AGENT);
    while (__hip_atomic_load(bar, __ATOMIC_ACQUIRE, __HIP_MEMORY_SCOPE_AGENT) < target)
      __builtin_amdgcn_s_sleep(2);
  }
  __syncthreads();
  __threadfence();
}

union SMem {
  struct { int sc_list[SC_CAP]; int sv_list[SV_CAP]; } l;  // tier-1/2 flush staging
  u64 shp[NTHREADS];                                       // rank phase
  struct {                                                 // tier-3 LDS subgraph
    u64 key[TN];                  // 16 KB
    int u_arr[TN];                //  8 KB
    int deg[TN];                  //  8 KB
    unsigned short adj[TN * TD];  // 32 KB
    int ov[OVCAP];                //  4 KB  (du<<16)|dw
    unsigned short tagl[TN];      //  4 KB
    unsigned int bits[TN / 32];   // 256 B  alive bitmask
    unsigned char isc[TN];        //  2 KB  is-centre (for ov kills)
  } t;                            // ~74 KB -> 2 blocks/CU (grid capped at 512 anyway)
};

__global__ void __launch_bounds__(NTHREADS, 8) cluster_kernel(Ctx c) {
  cg::grid_group grid = cg::this_grid();
  const int tid = blockIdx.x * blockDim.x + threadIdx.x;
  const int nthr = gridDim.x * blockDim.x;
  const int V = c.V, K = c.K;
  const int ql = threadIdx.x & 15;          // lane within quarter-wave
  const int bq = threadIdx.x >> 4;          // quarter id within block (64)
  const int NBQ = NTHREADS >> 4;

  __shared__ SMem sm;
  __shared__ int sc_cnt, sv_cnt, sc_base, sv_base, claim_sh;
  __shared__ int t_n, t_alive, t_fail, ov_cnt2;
  __shared__ int seg_hist[8];

  auto record_direct = [&](int v, u64 pv) {
    int slot = atomicAdd(&c.cnt[2], 1);
    int seg = 0;
    for (int t = 1; t < c.nseg; ++t) seg += (v >= c.row_splits[t]);
    c.centre_v[slot] = v;
    c.centre_key[slot] = ((u64)seg << 52) | pv;
    atomicAdd(&c.cnt[8 + seg], 1);
  };

  // Quarter-wave (16 lanes) per vertex: coalesced 64B row reads + 4 vertices
  // in flight per wave (r7 lesson: thread-per-vertex loses coalescing).
  auto phaseB = [&](const int* rl, int an, int r, int qstart, int qstride) {
    if (K == 96) {
      for (int i = qstart; i < an; i += qstride) {
        int u = rl ? rl[i] : i;
        u64 pu = pack_key(c.hier[u], u);
        if (c.assign[u] <= pu) continue;
        const int* row = c.neighs + (size_t)u * 96;
        int w[6];
#pragma unroll
        for (int t = 0; t < 6; ++t) w[t] = row[ql + 16 * t];
#pragma unroll
        for (int t = 0; t < 6; ++t)
          if (pack_key(c.hier[w[t]], w[t]) > pu) c.tag[w[t]] = r;
      }
    } else {
      for (int i = qstart; i < an; i += qstride) {
        int u = rl ? rl[i] : i;
        u64 pu = pack_key(c.hier[u], u);
        if (c.assign[u] <= pu) continue;
        const int* row = c.neighs + (size_t)u * K;
        for (int j = ql; j < K; j += 16) {
          int w = row[j];
          if (pack_key(c.hier[w], w) > pu) c.tag[w] = r;
        }
      }
    }
  };
  // Unguarded atomicMin grabs: junk values > target's own key are inert.
  auto phaseC = [&](const int* rl, int* wl, int* survc, int an, int r,
                    int qstart, int qstride) {
    for (int i = qstart; i < an; i += qstride) {
      int u = rl ? rl[i] : i;
      u64 pu = pack_key(c.hier[u], u);
      if (c.assign[u] <= pu) continue;
      if (c.tag[u] != r) {
        const int* row = c.neighs + (size_t)u * K;
        for (int j = ql; j < K; j += 16) atomicMin(&c.assign[row[j]], pu);
        if (ql == 0) {
          int s = atomicAdd(&sc_cnt, 1);
          if (s < SC_CAP) sm.l.sc_list[s] = u; else record_direct(u, pu);
        }
      } else if (ql == 0) {
        u64 y = __hip_atomic_load(&c.assign[u], __ATOMIC_RELAXED, __HIP_MEMORY_SCOPE_AGENT);
        if (y > pu) {
          int s = atomicAdd(&sv_cnt, 1);
          if (s < SV_CAP) sm.l.sv_list[s] = u;
          else { int g = atomicAdd(survc, 1); wl[g] = u; }
        }
      }
    }
  };
  auto flush_block = [&](int* wl, int* survc) {
    __syncthreads();
    int nsc = min(sc_cnt, SC_CAP), nsv = min(sv_cnt, SV_CAP);
    if (threadIdx.x == 0 && nsc) sc_base = atomicAdd(&c.cnt[2], nsc);
    if (threadIdx.x == 0 && nsv) sv_base = atomicAdd(survc, nsv);
    if (threadIdx.x < 8) seg_hist[threadIdx.x] = 0;
    __syncthreads();
    for (int i = threadIdx.x; i < nsv; i += blockDim.x) wl[sv_base + i] = sm.l.sv_list[i];
    for (int i = threadIdx.x; i < nsc; i += blockDim.x) {
      int v = sm.l.sc_list[i];
      int seg = 0;
      for (int t = 1; t < c.nseg; ++t) seg += (v >= c.row_splits[t]);
      c.centre_v[sc_base + i] = v;
      c.centre_key[sc_base + i] = ((u64)seg << 52) | pack_key(c.hier[v], v);
      atomicAdd(&seg_hist[seg], 1);
    }
    __syncthreads();
    if (threadIdx.x < c.nseg) {
      int h = seg_hist[threadIdx.x];
      if (h) atomicAdd(&c.cnt[8 + threadIdx.x], h);
    }
    __syncthreads();
    if (threadIdx.x == 0) { sc_cnt = 0; sv_cnt = 0; }
  };

  if (threadIdx.x == 0) { sc_cnt = 0; sv_cnt = 0; }

  // ================= tier 1: grid-sync rounds (huge frontiers) =================
  int aliveN = V, r = 0;
  {
    const int qg = tid >> 4, nq = nthr >> 4;
    while (true) {
      const int* rl = (r & 1) ? c.listA : c.listB;
      int* wl = (r & 1) ? c.listB : c.listA;
      if (tid == 0) c.cnt[(r + 1) & 1] = 0;
      phaseB(r ? rl : nullptr, aliveN, r, qg, nq);
      __threadfence();
      grid.sync();
      phaseC(r ? rl : nullptr, wl, &c.cnt[(r + 1) & 1], aliveN, r, qg, nq);
      flush_block(wl, &c.cnt[(r + 1) & 1]);
      __threadfence();
      grid.sync();
      aliveN = c.cnt[(r + 1) & 1];
      ++r;
      if (aliveN == 0 || aliveN <= T1 || r >= GRID_ROUND_CAP) break;
    }
  }

  // ================= tiers 2+3 =================
  if (aliveN > 0) {
    if (threadIdx.x == 0) claim_sh = atomicAdd(&c.cnt[4], 1);
    __syncthreads();
    const int trank = claim_sh;
    int an = aliveN, tr = r;

    // tier 2: TB2 blocks, spin barrier, mid frontiers
    if (trank < TB2 && an > T2) {
      const int qstart = trank * NBQ + bq;
      const int qstride = TB2 * NBQ;
      int ep = 0;
      while (true) {
        const int* rl = (tr & 1) ? c.listA : c.listB;
        int* wl = (tr & 1) ? c.listB : c.listA;
        if (trank == 0 && threadIdx.x == 0) c.cnt[(tr + 1) & 1] = 0;
        phaseB(rl, an, tr, qstart, qstride);
        xbar(&c.cnt[3], TB2 * (++ep));
        phaseC(rl, wl, &c.cnt[(tr + 1) & 1], an, tr, qstart, qstride);
        flush_block(wl, &c.cnt[(tr + 1) & 1]);
        xbar(&c.cnt[3], TB2 * (++ep));
        an = c.cnt[(tr + 1) & 1];
        ++tr;
        if (an == 0 || an <= T2 || tr >= MAX_ROUNDS) break;
      }
    }

    // tier 3: block 0, LDS-resident subgraph (zero global traffic per level
    // except one-shot centre grabs). Fallback to global rounds on overflow.
    if (trank == 0 && an > 0) {
      const int* rl = (tr & 1) ? c.listA : c.listB;
      bool use_lds = (an <= TN);
      int n = 0;
      if (use_lds) {
        if (threadIdx.x == 0) { t_n = 0; t_fail = 0; ov_cnt2 = 0; }
        __syncthreads();
        // entry: compact alive (fresh re-check) into dense LDS set
        for (int i = threadIdx.x; i < an; i += NTHREADS) {
          int u = rl[i];
          u64 pu = pack_key(c.hier[u], u);
          u64 y = __hip_atomic_load(&c.assign[u], __ATOMIC_RELAXED, __HIP_MEMORY_SCOPE_AGENT);
          if (y > pu) {
            int d = atomicAdd(&t_n, 1);
            sm.t.u_arr[d] = u;
            sm.t.key[d] = pu;
          }
        }
        __syncthreads();
        n = t_n;
        for (int i = threadIdx.x; i < TN / 32; i += NTHREADS) sm.t.bits[i] = 0;
        for (int d = threadIdx.x; d < n; d += NTHREADS) {
          c.dense_map[sm.t.u_arr[d]] = d;
          sm.t.deg[d] = 0;
          sm.t.tagl[d] = 0xFFFFu;
          sm.t.isc[d] = 0;
        }
        if (threadIdx.x == 0) t_alive = n;
        __syncthreads();
        for (int d = threadIdx.x; d < n; d += NTHREADS)
          atomicOr(&sm.t.bits[d >> 5], 1u << (d & 31));
        __syncthreads();
        // filtered adjacency: only later+alive-at-entry neighbours matter for
        // blocking; quarter-wave per dense vertex, 1 dense_map gather per edge.
        for (int d = bq; d < n; d += NBQ) {
          int u = sm.t.u_arr[d];
          u64 pu = sm.t.key[d];
          const int* row = c.neighs + (size_t)u * K;
          for (int j = ql; j < K; j += 16) {
            int w = row[j];
            int dw = c.dense_map[w];
            if (dw >= 0 && sm.t.key[dw] > pu) {
              int s = atomicAdd(&sm.t.deg[d], 1);
              if (s < TD) sm.t.adj[d * TD + s] = (unsigned short)dw;
              else {
                int o = atomicAdd(&ov_cnt2, 1);
                if (o < OVCAP) sm.t.ov[o] = (d << 16) | dw;
                else t_fail = 1;
              }
            }
          }
        }
        __syncthreads();
        if (t_fail) use_lds = false;
      }

      if (use_lds) {
        const int nov = min(ov_cnt2, OVCAP);
        int rounds = 0;
        while (t_alive > 0 && rounds < 4096) {
          const unsigned short tg = (unsigned short)(tr & 0xffff);
          // B: alive vertices tag their filtered (later+alive-at-entry) adj
          for (int d = threadIdx.x; d < n; d += NTHREADS) {
            if (sm.t.bits[d >> 5] & (1u << (d & 31))) {
              int dg = min(sm.t.deg[d], TD);
              for (int s = 0; s < dg; ++s) sm.t.tagl[sm.t.adj[d * TD + s]] = tg;
            }
          }
          for (int o = threadIdx.x; o < nov; o += NTHREADS) {
            int pr = sm.t.ov[o], df = pr >> 16;
            if (sm.t.bits[df >> 5] & (1u << (df & 31))) sm.t.tagl[pr & 0xffff] = tg;
          }
          __syncthreads();
          // C: untagged+alive -> centre. Kills are safe mid-phase: every kill
          // target was tagged this round (the centre was alive in B), so no
          // kill can change a decision.
          for (int d = threadIdx.x; d < n; d += NTHREADS) {
            if ((sm.t.bits[d >> 5] & (1u << (d & 31))) && sm.t.tagl[d] != tg) {
              sm.t.isc[d] = 1;
              unsigned int m = 1u << (d & 31);
              unsigned int old = atomicAnd(&sm.t.bits[d >> 5], ~m);
              if (old & m) atomicSub(&t_alive, 1);
              int u = sm.t.u_arr[d];
              u64 pu = sm.t.key[d];
              const int* row = c.neighs + (size_t)u * K;   // L2-hot
              for (int j = 0; j < K; ++j) atomicMin(&c.assign[row[j]], pu);
              record_direct(u, pu);
              int dg = min(sm.t.deg[d], TD);
              for (int s = 0; s < dg; ++s) {
                int dw = sm.t.adj[d * TD + s];
                unsigned int mw = 1u << (dw & 31);
                unsigned int ow = atomicAnd(&sm.t.bits[dw >> 5], ~mw);
                if (ow & mw) atomicSub(&t_alive, 1);
              }
            }
          }
          __syncthreads();
          // K: overflow-edge kills by centres (historical re-kills harmless)
          for (int o = threadIdx.x; o < nov; o += NTHREADS) {
            int pr = sm.t.ov[o];
            if (sm.t.isc[pr >> 16]) {
              int dw = pr & 0xffff;
              unsigned int mw = 1u << (dw & 31);
              unsigned int ow = atomicAnd(&sm.t.bits[dw >> 5], ~mw);
              if (ow & mw) atomicSub(&t_alive, 1);
            }
          }
          __syncthreads();
          ++tr; ++rounds;
        }
      } else {
        // global fallback (r8 tier-3): single block, global tag/list rounds
        while (an > 0 && tr < MAX_ROUNDS) {
          const int* frl = (tr & 1) ? c.listA : c.listB;
          int* fwl = (tr & 1) ? c.listB : c.listA;
          if (threadIdx.x == 0) c.cnt[(tr + 1) & 1] = 0;
          phaseB(frl, an, tr, bq, NBQ);
          __threadfence(); __syncthreads();
          phaseC(frl, fwl, &c.cnt[(tr + 1) & 1], an, tr, bq, NBQ);
          flush_block(fwl, &c.cnt[(tr + 1) & 1]);
          __threadfence(); __syncthreads();
          an = c.cnt[(tr + 1) & 1];
          ++tr;
        }
      }
    }
  }
  __threadfence();
  grid.sync();

  // ================= centre ranks: O(nC^2) LDS-tiled counting =================
  int nC = c.cnt[2];
  if ((long long)blockIdx.x * blockDim.x < (long long)nC) {
    bool have = tid < nC;
    u64 mykey = have ? c.centre_key[tid] : 0;
    int myv = have ? c.centre_v[tid] : 0;
    int myrank = 0;
    for (int cs = 0; cs < nC; cs += NTHREADS) {
      int j = cs + threadIdx.x;
      sm.shp[threadIdx.x] = (j < nC) ? c.centre_key[j] : ~0ull;
      __syncthreads();
      int lim = min(NTHREADS, nC - cs);
      for (int t = 0; t < lim; ++t) myrank += (sm.shp[t] < mykey) ? 1 : 0;
      __syncthreads();
    }
    if (have) {
      c.out_sel[myrank] = myv;     // rank among centre keys == cumsum position
      c.rank_of[myv] = myrank;
    }
  }
  if (tid == 0) {
    int run = 0;
    c.out_rs[0] = 0;
    for (int s = 0; s < c.nseg; ++s) { run += c.cnt[8 + s]; c.out_rs[s + 1] = run; }
  }
  __threadfence();
  grid.sync();

  // ================= ggather =================
  for (int v = tid; v < V; v += nthr) {
    u64 y = c.assign[v];
    u64 pv = pack_key(c.hier[v], v);
    int ctr = (y < pv) ? (int)(y & IDX_MASK) : v;   // y==pv -> centre -> self
    c.out_gg[v] = c.rank_of[ctr];
  }
}

extern "C" void kernel_launch(void* const* d_in, const int* in_sizes, int n_in,
                              void* d_out, int out_size, void* d_ws, size_t ws_size,
                              hipStream_t stream) {
  Ctx c;
  c.neighs = (const int*)d_in[0];
  c.hier = (const float*)d_in[1];
  c.row_splits = (const int*)d_in[2];
  c.V = in_sizes[1];
  c.K = in_sizes[0] / c.V;
  c.nseg = in_sizes[2] - 1;

  char* pm = (char*)d_ws;
  const size_t V = (size_t)c.V;
  c.assign = (u64*)pm;        pm += V * 8;
  c.tag = (int*)pm;           pm += V * 4;
  c.dense_map = (int*)pm;     pm += V * 4;
  size_t ff_bytes = V * 16;   // assign -> ~0 (alive), tag -> -1, dense_map -> -1
  c.listA = (int*)pm;         pm += V * 4;
  c.listB = (int*)pm;         pm += V * 4;
  c.centre_key = (u64*)pm;    pm += V * 8;
  c.centre_v = (int*)pm;      pm += V * 4;
  c.rank_of = (int*)pm;       pm += V * 4;
  c.cnt = (int*)pm;           pm += 64 * 4;

  int* out = (int*)d_out;
  c.out_sel = out;
  c.out_rs = out + c.V;
  c.out_gg = out + c.V + c.nseg + 1;

  hipMemsetAsync(d_ws, 0xFF, ff_bytes, stream);
  hipMemsetAsync((void*)c.cnt, 0, 64 * 4, stream);
  hipMemsetAsync((void*)c.out_sel, 0xFF, V * 4, stream);

  int dev = 0, nCU = 0, maxB = 0;
  hipGetDevice(&dev);
  hipDeviceGetAttribute(&nCU, hipDeviceAttributeMultiprocessorCount, dev);
  hipOccupancyMaxActiveBlocksPerMultiprocessor(&maxB, cluster_kernel, NTHREADS, 0);
  if (nCU <= 0) nCU = 256;
  if (maxB <= 0) maxB = 1;
  int grid = nCU * maxB;
  if (grid > MAX_GRID) grid = MAX_GRID;

  void* args[] = { &c };
  hipLaunchCooperativeKernel((void*)cluster_kernel, dim3(grid), dim3(NTHREADS),
                             args, 0, stream);
}

// Round 11
// 2012.902 us; speedup vs baseline: 1.2813x; 1.1677x over previous
//
#include <hip/hip_runtime.h>
#include <hip/hip_cooperative_groups.h>

namespace cg = cooperative_groups;

#define IDX_BITS 20
#define IDX_MASK ((1u << IDX_BITS) - 1)
#define NT1 1024
#define MAX_G1 512
#define T1 49152          // tier-1 (grid-sync) while alive > T1
#define TB2 16            // tier-2 block count (r9: >16 spin blocks regress)
#define T2 1536           // tier-2 while alive > T2; below: single-block tier-3
#define GRID_ROUND_CAP 16
#define MAX_ROUNDS 8000
#define SC_CAP 1024
#define SV_CAP 4096

typedef unsigned long long u64;

// All edges are intra-segment, so the per-edge comparison key drops seg:
// key = (~float_bits(hier) << 20) | v ; smaller = earlier in processing order.
__device__ __forceinline__ u64 pack_key(float h, int v) {
  return ((u64)(~__float_as_uint(h)) << IDX_BITS) | (unsigned)v;
}

struct Ctx {
  const int* __restrict__ neighs;
  const float* __restrict__ hier;
  const int* __restrict__ row_splits;
  int V, K, nseg;
  u64* assign;       // [V] min grabber key; ~0 = alive; == own key -> decided centre
  int* tag;          // [V] "blocked at round r" stamps (plain racy stores of r)
  int* listA;        // [V] frontier ping
  int* listB;        // [V] frontier pong
  u64* centre_key;   // [V] full key incl. seg (for global ranking)
  int* centre_v;     // [V]
  int* rank_of;      // [V]
  int* cnt;          // [0,1] survivor ctrs (parity), [2] nC, [3] xbar, [5] aliveN, [6] round, [8+s] seg
  int* out_sel;
  int* out_rs;
  int* out_gg;
};

struct BlkState {
  int sc_cnt, sv_cnt, sc_base, sv_base;
  int seg_hist[8];
  int sc_list[SC_CAP];
  int sv_list[SV_CAP];
};

// Monotonic arrive-counter barrier for the TB2 group (all co-resident).
__device__ __forceinline__ void xbar(int* bar, int target) {
  __syncthreads();
  __threadfence();
  if (threadIdx.x == 0) {
    __hip_atomic_fetch_add(bar, 1, __ATOMIC_RELEASE, __HIP_MEMORY_SCOPE_AGENT);
    while (__hip_atomic_load(bar, __ATOMIC_ACQUIRE, __HIP_MEMORY_SCOPE_AGENT) < target)
      __builtin_amdgcn_s_sleep(2);
  }
  __syncthreads();
  __threadfence();
}

__device__ __forceinline__ void record_direct(const Ctx& c, int v, u64 pv) {
  int slot = atomicAdd(&c.cnt[2], 1);
  int seg = 0;
  for (int t = 1; t < c.nseg; ++t) seg += (v >= c.row_splits[t]);
  c.centre_v[slot] = v;
  c.centre_key[slot] = ((u64)seg << 52) | pv;
  atomicAdd(&c.cnt[8 + seg], 1);
}

// Quarter-wave (16 lanes) per vertex: coalesced 64B row reads, 4 vertices in
// flight per wave (r7 lesson: thread-per-vertex loses coalescing).
__device__ __forceinline__ void phaseB(const Ctx& c, const int* rl, int an, int r,
                                       int qs, int qst, int ql) {
  if (c.K == 96) {
    for (int i = qs; i < an; i += qst) {
      int u = rl ? rl[i] : i;
      u64 pu = pack_key(c.hier[u], u);
      if (c.assign[u] <= pu) continue;
      const int* row = c.neighs + (size_t)u * 96;
      int w[6];
#pragma unroll
      for (int t = 0; t < 6; ++t) w[t] = row[ql + 16 * t];
#pragma unroll
      for (int t = 0; t < 6; ++t)
        if (pack_key(c.hier[w[t]], w[t]) > pu) c.tag[w[t]] = r;
    }
  } else {
    for (int i = qs; i < an; i += qst) {
      int u = rl ? rl[i] : i;
      u64 pu = pack_key(c.hier[u], u);
      if (c.assign[u] <= pu) continue;
      const int* row = c.neighs + (size_t)u * c.K;
      for (int j = ql; j < c.K; j += 16) {
        int w = row[j];
        if (pack_key(c.hier[w], w) > pu) c.tag[w] = r;
      }
    }
  }
}

// Unguarded atomicMin grabs: junk values > target's own key are inert.
__device__ __forceinline__ void phaseC(const Ctx& c, BlkState& bs, const int* rl,
                                       int* wl, int* survc, int an, int r,
                                       int qs, int qst, int ql) {
  for (int i = qs; i < an; i += qst) {
    int u = rl ? rl[i] : i;
    u64 pu = pack_key(c.hier[u], u);
    if (c.assign[u] <= pu) continue;
    if (c.tag[u] != r) {
      const int* row = c.neighs + (size_t)u * c.K;
      for (int j = ql; j < c.K; j += 16) atomicMin(&c.assign[row[j]], pu);
      if (ql == 0) {
        int s = atomicAdd(&bs.sc_cnt, 1);
        if (s < SC_CAP) bs.sc_list[s] = u; else record_direct(c, u, pu);
      }
    } else if (ql == 0) {
      // fresh agent-scope re-check trims stale listings of same-round grabs
      u64 y = __hip_atomic_load(&c.assign[u], __ATOMIC_RELAXED, __HIP_MEMORY_SCOPE_AGENT);
      if (y > pu) {
        int s = atomicAdd(&bs.sv_cnt, 1);
        if (s < SV_CAP) bs.sv_list[s] = u;
        else { int g = atomicAdd(survc, 1); wl[g] = u; }
      }
    }
  }
}

__device__ __forceinline__ void flush_block(const Ctx& c, BlkState& bs, int* wl, int* survc) {
  __syncthreads();
  int nsc = min(bs.sc_cnt, SC_CAP), nsv = min(bs.sv_cnt, SV_CAP);
  if (threadIdx.x == 0 && nsc) bs.sc_base = atomicAdd(&c.cnt[2], nsc);
  if (threadIdx.x == 0 && nsv) bs.sv_base = atomicAdd(survc, nsv);
  if (threadIdx.x < 8) bs.seg_hist[threadIdx.x] = 0;
  __syncthreads();
  for (int i = threadIdx.x; i < nsv; i += blockDim.x) wl[bs.sv_base + i] = bs.sv_list[i];
  for (int i = threadIdx.x; i < nsc; i += blockDim.x) {
    int v = bs.sc_list[i];
    int seg = 0;
    for (int t = 1; t < c.nseg; ++t) seg += (v >= c.row_splits[t]);
    c.centre_v[bs.sc_base + i] = v;
    c.centre_key[bs.sc_base + i] = ((u64)seg << 52) | pack_key(c.hier[v], v);
    atomicAdd(&bs.seg_hist[seg], 1);
  }
  __syncthreads();
  if (threadIdx.x < c.nseg) {
    int h = bs.seg_hist[threadIdx.x];
    if (h) atomicAdd(&c.cnt[8 + threadIdx.x], h);
  }
  __syncthreads();
  if (threadIdx.x == 0) { bs.sc_cnt = 0; bs.sv_cnt = 0; }
}

// ============ K1: tier-1 grid-sync rounds (huge frontiers) ============
__global__ void __launch_bounds__(NT1) k_tier1(Ctx c) {
  cg::grid_group grid = cg::this_grid();
  __shared__ BlkState bs;
  const int tid = blockIdx.x * blockDim.x + threadIdx.x;
  const int nthr = gridDim.x * blockDim.x;
  const int ql = threadIdx.x & 15;
  const int qg = tid >> 4, nq = nthr >> 4;
  if (threadIdx.x == 0) { bs.sc_cnt = 0; bs.sv_cnt = 0; }
  __syncthreads();

  int aliveN = c.V, r = 0;
  while (true) {
    const int* rl = (r & 1) ? c.listA : c.listB;
    int* wl = (r & 1) ? c.listB : c.listA;
    if (tid == 0) c.cnt[(r + 1) & 1] = 0;   // 2 syncs since that slot's last read
    phaseB(c, r ? rl : nullptr, aliveN, r, qg, nq, ql);
    __threadfence();
    grid.sync();
    phaseC(c, bs, r ? rl : nullptr, wl, &c.cnt[(r + 1) & 1], aliveN, r, qg, nq, ql);
    flush_block(c, bs, wl, &c.cnt[(r + 1) & 1]);
    __threadfence();
    grid.sync();
    aliveN = c.cnt[(r + 1) & 1];
    ++r;
    if (aliveN == 0 || aliveN <= T1 || r >= GRID_ROUND_CAP) break;
  }
  if (tid == 0) { c.cnt[5] = aliveN; c.cnt[6] = r; }
}

// ============ K2: tier-2 (16-block spin rounds) + tier-3 (block-0 tail) ============
__global__ void __launch_bounds__(NT1) k_tail(Ctx c) {
  __shared__ BlkState bs;
  const int ql = threadIdx.x & 15;
  const int bq = threadIdx.x >> 4;
  const int NBQ = NT1 >> 4;
  const int trank = blockIdx.x;
  if (threadIdx.x == 0) { bs.sc_cnt = 0; bs.sv_cnt = 0; }
  __syncthreads();

  int an = c.cnt[5], tr = c.cnt[6];

  if (an > T2) {
    const int qstart = trank * NBQ + bq;
    const int qstride = TB2 * NBQ;
    int ep = 0;
    while (true) {
      const int* rl = (tr & 1) ? c.listA : c.listB;
      int* wl = (tr & 1) ? c.listB : c.listA;
      if (trank == 0 && threadIdx.x == 0) c.cnt[(tr + 1) & 1] = 0;
      phaseB(c, rl, an, tr, qstart, qstride, ql);
      xbar(&c.cnt[3], TB2 * (++ep));
      phaseC(c, bs, rl, wl, &c.cnt[(tr + 1) & 1], an, tr, qstart, qstride, ql);
      flush_block(c, bs, wl, &c.cnt[(tr + 1) & 1]);
      xbar(&c.cnt[3], TB2 * (++ep));
      an = c.cnt[(tr + 1) & 1];
      ++tr;
      if (an == 0 || an <= T2 || tr >= MAX_ROUNDS) break;
    }
  }
  if (trank != 0) return;

  // tier-3: block 0 alone, compacted-list rounds with ~0.3us barriers (r8 form)
  while (an > 0 && tr < MAX_ROUNDS) {
    const int* rl = (tr & 1) ? c.listA : c.listB;
    int* wl = (tr & 1) ? c.listB : c.listA;
    if (threadIdx.x == 0) c.cnt[(tr + 1) & 1] = 0;
    phaseB(c, rl, an, tr, bq, NBQ, ql);
    __threadfence(); __syncthreads();     // L1 inv: see own block's L2 atomics
    phaseC(c, bs, rl, wl, &c.cnt[(tr + 1) & 1], an, tr, bq, NBQ, ql);
    flush_block(c, bs, wl, &c.cnt[(tr + 1) & 1]);
    __threadfence(); __syncthreads();
    an = c.cnt[(tr + 1) & 1];
    ++tr;
  }
}

// ============ K3: centre ranks (O(nC^2) LDS-tiled) + row splits ============
__global__ void __launch_bounds__(NT1) k_rank(Ctx c) {
  __shared__ u64 shp[NT1];
  const int nC = c.cnt[2];
  for (int base = blockIdx.x * NT1; base < nC; base += gridDim.x * NT1) {
    int idx = base + threadIdx.x;
    bool have = idx < nC;
    u64 mykey = have ? c.centre_key[idx] : 0;
    int myv = have ? c.centre_v[idx] : 0;
    int myrank = 0;
    for (int cs = 0; cs < nC; cs += NT1) {
      int j = cs + threadIdx.x;
      shp[threadIdx.x] = (j < nC) ? c.centre_key[j] : ~0ull;
      __syncthreads();
      int lim = min(NT1, nC - cs);
      for (int t = 0; t < lim; ++t) myrank += (shp[t] < mykey) ? 1 : 0;
      __syncthreads();
    }
    if (have) {
      c.out_sel[myrank] = myv;   // rank among centre keys == cumsum position
      c.rank_of[myv] = myrank;
    }
  }
  if (blockIdx.x == 0 && threadIdx.x == 0) {
    int run = 0;
    c.out_rs[0] = 0;
    for (int s = 0; s < c.nseg; ++s) { run += c.cnt[8 + s]; c.out_rs[s + 1] = run; }
  }
}

// ============ K4: ggather ============
__global__ void __launch_bounds__(256) k_gg(Ctx c) {
  int v = blockIdx.x * blockDim.x + threadIdx.x;
  const int stride = gridDim.x * blockDim.x;
  for (; v < c.V; v += stride) {
    u64 y = c.assign[v];
    u64 pv = pack_key(c.hier[v], v);
    int ctr = (y < pv) ? (int)(y & IDX_MASK) : v;   // y==pv -> centre -> self
    c.out_gg[v] = c.rank_of[ctr];
  }
}

extern "C" void kernel_launch(void* const* d_in, const int* in_sizes, int n_in,
                              void* d_out, int out_size, void* d_ws, size_t ws_size,
                              hipStream_t stream) {
  Ctx c;
  c.neighs = (const int*)d_in[0];
  c.hier = (const float*)d_in[1];
  c.row_splits = (const int*)d_in[2];
  c.V = in_sizes[1];
  c.K = in_sizes[0] / c.V;
  c.nseg = in_sizes[2] - 1;

  char* pm = (char*)d_ws;
  const size_t V = (size_t)c.V;
  c.assign = (u64*)pm;        pm += V * 8;
  c.tag = (int*)pm;           pm += V * 4;
  size_t ff_bytes = V * 12;   // assign -> ~0 (alive), tag -> -1
  c.listA = (int*)pm;         pm += V * 4;
  c.listB = (int*)pm;         pm += V * 4;
  c.centre_key = (u64*)pm;    pm += V * 8;
  c.centre_v = (int*)pm;      pm += V * 4;
  c.rank_of = (int*)pm;       pm += V * 4;
  c.cnt = (int*)pm;           pm += 64 * 4;

  int* out = (int*)d_out;
  c.out_sel = out;
  c.out_rs = out + c.V;
  c.out_gg = out + c.V + c.nseg + 1;

  hipMemsetAsync(d_ws, 0xFF, ff_bytes, stream);
  hipMemsetAsync((void*)c.cnt, 0, 64 * 4, stream);
  hipMemsetAsync((void*)c.out_sel, 0xFF, V * 4, stream);

  int dev = 0, nCU = 0, maxB = 0;
  hipGetDevice(&dev);
  hipDeviceGetAttribute(&nCU, hipDeviceAttributeMultiprocessorCount, dev);
  hipOccupancyMaxActiveBlocksPerMultiprocessor(&maxB, k_tier1, NT1, 0);
  if (nCU <= 0) nCU = 256;
  if (maxB <= 0) maxB = 1;
  int g1 = nCU * maxB;
  if (g1 > MAX_G1) g1 = MAX_G1;

  void* args[] = { &c };
  hipLaunchCooperativeKernel((void*)k_tier1, dim3(g1), dim3(NT1), args, 0, stream);
  k_tail<<<TB2, NT1, 0, stream>>>(c);
  k_rank<<<16, NT1, 0, stream>>>(c);
  k_gg<<<512, 256, 0, stream>>>(c);
}